// Round 3
// baseline (316.582 us; speedup 1.0000x reference)
//
#include <hip/hip_runtime.h>
#include <cstdint>
#include <cstddef>

#define NPTS 4096
#define KNN  16
#define INV_DEG (1.0f / 17.0f)
#define CAP  48    // knn per-point candidate buffer
#define TS   1024  // candidate coord tile size (12 KB LDS)

typedef unsigned long long u64;
typedef unsigned int u32;
typedef float v2f __attribute__((ext_vector_type(2)));

__device__ __forceinline__ u32 mapmono(float f) {
  u32 u = __float_as_uint(f);
  return u ^ ((u32)((int)u >> 31) | 0x80000000u);
}
__device__ __forceinline__ float unmapmono(u32 m) {
  u32 u = (m & 0x80000000u) ? (m ^ 0x80000000u) : ~m;
  return __uint_as_float(u);
}
__device__ __forceinline__ u64 u64min(u64 a, u64 b) { return a < b ? a : b; }
__device__ __forceinline__ u64 u64max(u64 a, u64 b) { return a > b ? a : b; }

// Full 64-lane bitonic sort, ascending by lane (verified in R1).
__device__ __forceinline__ u64 bitonic64(u64 key, int lane) {
#pragma unroll
  for (int k = 2; k <= 64; k <<= 1) {
#pragma unroll
    for (int m = k >> 1; m >= 1; m >>= 1) {
      u64 partner = __shfl_xor(key, m, 64);
      bool up = ((lane & k) == 0);
      bool lower = ((lane & m) == 0);
      u64 mn = u64min(key, partner);
      u64 mx = u64max(key, partner);
      key = (lower == up) ? mn : mx;
    }
  }
  return key;
}

// ---------------------------------------------------------------------------
// K1: exact KNN. Wave handles 4 points/pass (x2 passes). Candidate coords
// tiled through LDS (24 KB total -> 6 blocks/CU by LDS; target 24 waves/CU).
// Hot loop: float-threshold filter; selection via register bitonic-64 merge
// of {16 slots} U {<=48 buffered keys}. Ties -> lower index (key low32).
// ---------------------------------------------------------------------------
__global__ __launch_bounds__(512, 6) void knn_kernel(const float* __restrict__ feats,
                                                     int* __restrict__ nbr) {
#pragma clang fp contract(off)
  __shared__ float sx[TS], sy[TS], sz[TS];  // 12 KB
  __shared__ u64 sbuf[8][4][CAP];           // 12 KB

  const int b = blockIdx.x >> 6;
  const int pbase = (blockIdx.x & 63) * 64;
  const float* fb = feats + (size_t)b * NPTS * 6;
  const int wave = threadIdx.x >> 6;
  const int lane = threadIdx.x & 63;

  for (int g = 0; g < 2; ++g) {
    int ip[4];
    float xi[4], yi[4], zi[4], sqi[4], tau[4];
    u64 slot[4];
    int cnt[4];
#pragma unroll
    for (int p = 0; p < 4; ++p) {
      ip[p] = pbase + wave * 8 + g * 4 + p;
      const float* fr = fb + (size_t)ip[p] * 6;
      xi[p] = fr[0]; yi[p] = fr[1]; zi[p] = fr[2];
      sqi[p] = __fadd_rn(__fadd_rn(__fmul_rn(xi[p], xi[p]), __fmul_rn(yi[p], yi[p])),
                         __fmul_rn(zi[p], zi[p]));
      tau[p] = __uint_as_float(0x7f800000u);
      slot[p] = ~0ull;
      cnt[p] = 0;
    }

    auto flush = [&](int p, bool fin) {
      u64 key;
      if (lane < 16) {
        key = slot[p];
      } else {
        const int idx = lane - 16;
        key = (idx < cnt[p]) ? sbuf[wave][p][idx] : ~0ull;
      }
      if ((u32)key == (u32)ip[p]) key = ~0ull;  // neutralize self
      key = bitonic64(key, lane);
      if (fin) {
        if (lane < KNN)
          nbr[((size_t)(b * NPTS) + ip[p]) * KNN + lane] = (int)(u32)key;
      } else {
        if (lane < 16) slot[p] = key;
        tau[p] = unmapmono((u32)(__shfl(key, 15, 64) >> 32));
      }
      cnt[p] = 0;
    };

    for (int tb = 0; tb < NPTS; tb += TS) {
      __syncthreads();  // protect restage (prev pass readers done)
      for (int t = threadIdx.x; t < TS; t += 512) {
        const float* fr = fb + (size_t)(tb + t) * 6;
        sx[t] = fr[0]; sy[t] = fr[1]; sz[t] = fr[2];
      }
      __syncthreads();

      for (int jb0 = 0; jb0 < TS; jb0 += 64) {
        const int tl = jb0 + lane;
        const int j = tb + tl;
        const float cx = sx[tl], cy = sy[tl], cz = sz[tl];
        const float sqj = __fadd_rn(__fadd_rn(__fmul_rn(cx, cx), __fmul_rn(cy, cy)),
                                    __fmul_rn(cz, cz));
        if (tb == 0 && jb0 == 0) {
          // bootstrap: all 64 candidates, direct register sort
#pragma unroll
          for (int p = 0; p < 4; ++p) {
            float dot = __fmul_rn(xi[p], cx);
            dot = __fmaf_rn(yi[p], cy, dot);
            dot = __fmaf_rn(zi[p], cz, dot);
            const float d2 = __fsub_rn(__fadd_rn(sqi[p], sqj), __fmul_rn(2.0f, dot));
            u64 key = ((u64)mapmono(d2) << 32) | (u32)j;
            if (j == ip[p]) key = ~0ull;
            key = bitonic64(key, lane);
            if (lane < 16) slot[p] = key;
            tau[p] = unmapmono((u32)(__shfl(key, 15, 64) >> 32));
          }
          continue;
        }

        const v2f cx2 = {cx, cx}, cy2 = {cy, cy}, cz2 = {cz, cz}, sq2 = {sqj, sqj};
        float d2s[4];
#pragma unroll
        for (int pp = 0; pp < 2; ++pp) {
          v2f X = {xi[2 * pp], xi[2 * pp + 1]};
          v2f Y = {yi[2 * pp], yi[2 * pp + 1]};
          v2f Z = {zi[2 * pp], zi[2 * pp + 1]};
          v2f SQ = {sqi[2 * pp], sqi[2 * pp + 1]};
          v2f dot = X * cx2;
          dot = __builtin_elementwise_fma(Y, cy2, dot);
          dot = __builtin_elementwise_fma(Z, cz2, dot);
          v2f two = {2.0f, 2.0f};
          v2f d2 = (SQ + sq2) - two * dot;  // contract(off): rn each op
          d2s[2 * pp] = d2.x;
          d2s[2 * pp + 1] = d2.y;
        }
#pragma unroll
        for (int p = 0; p < 4; ++p) {
          const bool pred = d2s[p] <= tau[p];
          const u64 bal = __ballot(pred);
          if (bal) {
            const int npass = __popcll(bal);
            if (cnt[p] + npass > CAP) flush(p, false);
            const int pos = cnt[p] + (int)__builtin_amdgcn_mbcnt_hi(
                                          (u32)(bal >> 32),
                                          __builtin_amdgcn_mbcnt_lo((u32)bal, 0));
            const u64 key = ((u64)mapmono(d2s[p]) << 32) | (u32)j;
            if (npass <= CAP) {
              if (pred) sbuf[wave][p][pos] = key;
              cnt[p] += npass;
            } else {  // pathological: npass in (48,64]
              if (pred && pos < CAP) sbuf[wave][p][pos] = key;
              cnt[p] = CAP;
              flush(p, false);
              if (pred && pos >= CAP) sbuf[wave][p][pos - CAP] = key;
              cnt[p] = npass - CAP;
            }
          }
        }
      }
    }
#pragma unroll
    for (int p = 0; p < 4; ++p) flush(p, true);
  }
}

// ---------------------------------------------------------------------------
// T1: x1 = relu(((feats + sum_nbr feats) @ W1) * inv_deg + b1).  64 pts/block.
// ---------------------------------------------------------------------------
__global__ __launch_bounds__(256) void enc1_kernel(const float* __restrict__ feats,
                                                   const int* __restrict__ nbr,
                                                   const float* __restrict__ W1,
                                                   const float* __restrict__ b1,
                                                   float* __restrict__ x1) {
  __shared__ float af[64][6];
  const int tid = threadIdx.x;
  const int n0 = blockIdx.x * 64;
  const int gb = n0 & ~(NPTS - 1);

  if (tid < 128) {
    const int p = tid >> 1, h = tid & 1;
    const int n = n0 + p;
    const int d0 = h * 3;
    const int* nb = nbr + (size_t)n * KNN;
    const float* fr = feats + (size_t)n * 6 + d0;
    float a0 = fr[0], a1 = fr[1], a2 = fr[2];
#pragma unroll
    for (int t = 0; t < KNN; ++t) {
      const float* fq = feats + (size_t)(gb + nb[t]) * 6 + d0;
      a0 += fq[0]; a1 += fq[1]; a2 += fq[2];
    }
    af[p][d0] = a0; af[p][d0 + 1] = a1; af[p][d0 + 2] = a2;
  }
  __syncthreads();

  const int c = tid & 63, pg = tid >> 6;
  float w[6];
#pragma unroll
  for (int k = 0; k < 6; ++k) w[k] = W1[k * 64 + c];
  const float bv = b1[c];
  for (int pi = 0; pi < 16; ++pi) {
    const int p = pg * 16 + pi;
    float s = 0.f;
#pragma unroll
    for (int k = 0; k < 6; ++k) s = fmaf(af[p][k], w[k], s);
    x1[(size_t)(n0 + p) * 64 + c] = fmaxf(fmaf(s, INV_DEG, bv), 0.f);
  }
}

// ---------------------------------------------------------------------------
// T2: x2 = relu(((x1 + sum_nbr x1) @ W2) * inv_deg + b2).  16 pts/block.
// W2 staged paired in LDS; k-loop: broadcast a via ds_read_b128, v_pk_fma.
// ---------------------------------------------------------------------------
__global__ __launch_bounds__(256) void enc2_kernel(const float* __restrict__ x1,
                                                   const int* __restrict__ nbr,
                                                   const float* __restrict__ W2,
                                                   const float* __restrict__ b2,
                                                   float* __restrict__ x2) {
  __shared__ float a1s[16][64];  // 4 KB
  __shared__ v2f w2s[64][64];    // 32 KB: w2s[k][l] = (W2[k][l], W2[k][l+64])
  const int tid = threadIdx.x;
  const int n0 = blockIdx.x * 16;
  const int gb = n0 & ~(NPTS - 1);

#pragma unroll
  for (int i = 0; i < 16; ++i) {
    const int e = tid + 256 * i;
    const int k = e >> 6, l = e & 63;
    v2f w;
    w.x = W2[k * 128 + l];
    w.y = W2[k * 128 + 64 + l];
    w2s[k][l] = w;
  }
  {
    const int p = tid >> 4, c4 = tid & 15;
    const int n = n0 + p;
    const int* nb = nbr + (size_t)n * KNN;
    float4 s = ((const float4*)(x1 + (size_t)n * 64))[c4];
#pragma unroll
    for (int t = 0; t < KNN; ++t) {
      float4 v = ((const float4*)(x1 + (size_t)(gb + nb[t]) * 64))[c4];
      s.x += v.x; s.y += v.y; s.z += v.z; s.w += v.w;
    }
    *((float4*)&a1s[p][c4 * 4]) = s;
  }
  __syncthreads();

  const int wave = tid >> 6, lane = tid & 63;
  const int p0 = wave * 4;
  const float bx = b2[lane], by = b2[lane + 64];
  v2f acc0 = {0, 0}, acc1 = {0, 0}, acc2 = {0, 0}, acc3 = {0, 0};
  for (int k = 0; k < 64; k += 4) {
    const float4 a0 = *(const float4*)&a1s[p0 + 0][k];
    const float4 a1v = *(const float4*)&a1s[p0 + 1][k];
    const float4 a2v = *(const float4*)&a1s[p0 + 2][k];
    const float4 a3v = *(const float4*)&a1s[p0 + 3][k];
#pragma unroll
    for (int kk = 0; kk < 4; ++kk) {
      const v2f w = w2s[k + kk][lane];
      const float e0 = kk == 0 ? a0.x : kk == 1 ? a0.y : kk == 2 ? a0.z : a0.w;
      const float e1 = kk == 0 ? a1v.x : kk == 1 ? a1v.y : kk == 2 ? a1v.z : a1v.w;
      const float e2 = kk == 0 ? a2v.x : kk == 1 ? a2v.y : kk == 2 ? a2v.z : a2v.w;
      const float e3 = kk == 0 ? a3v.x : kk == 1 ? a3v.y : kk == 2 ? a3v.z : a3v.w;
      v2f v0 = {e0, e0}, v1 = {e1, e1}, v2 = {e2, e2}, v3 = {e3, e3};
      acc0 = __builtin_elementwise_fma(v0, w, acc0);
      acc1 = __builtin_elementwise_fma(v1, w, acc1);
      acc2 = __builtin_elementwise_fma(v2, w, acc2);
      acc3 = __builtin_elementwise_fma(v3, w, acc3);
    }
  }
  v2f accs[4] = {acc0, acc1, acc2, acc3};
#pragma unroll
  for (int pi = 0; pi < 4; ++pi) {
    float* row = x2 + (size_t)(n0 + p0 + pi) * 128;
    row[lane] = fmaxf(fmaf(accs[pi].x, INV_DEG, bx), 0.f);
    row[lane + 64] = fmaxf(fmaf(accs[pi].y, INV_DEG, by), 0.f);
  }
}

// ---------------------------------------------------------------------------
// T3: out = x2 @ Wf + bf (K=128). Split-K across wave pairs, Wf in VGPRs
// (64 v2f/wave), x2 staged in LDS (in-place safe on d_out).
// ---------------------------------------------------------------------------
__global__ __launch_bounds__(256) void enc3_kernel(const float* __restrict__ x2,
                                                   const float* __restrict__ Wf,
                                                   const float* __restrict__ bf,
                                                   float* __restrict__ out) {
  __shared__ float xs[16 * 128];      // 8 KB
  __shared__ float part[2][16][128];  // 16 KB
  const int tid = threadIdx.x;
  const int n0 = blockIdx.x * 16;

#pragma unroll
  for (int i = 0; i < 2; ++i) {
    const int e = tid + 256 * i;
    ((float4*)xs)[e] = ((const float4*)(x2 + (size_t)n0 * 128))[e];
  }

  const int wave = tid >> 6, lane = tid & 63;
  const int kh = wave & 1, pg = wave >> 1;
  v2f w[64];
#pragma unroll
  for (int j = 0; j < 64; ++j) {
    const int k = kh * 64 + j;
    w[j].x = Wf[k * 128 + lane];
    w[j].y = Wf[k * 128 + 64 + lane];
  }
  __syncthreads();

  for (int pi = 0; pi < 8; ++pi) {
    const int p = pg * 8 + pi;
    v2f acc = {0, 0};
    for (int j = 0; j < 64; j += 4) {
      const float4 a = *(const float4*)&xs[p * 128 + kh * 64 + j];
#pragma unroll
      for (int jj = 0; jj < 4; ++jj) {
        const float e = jj == 0 ? a.x : jj == 1 ? a.y : jj == 2 ? a.z : a.w;
        v2f v = {e, e};
        acc = __builtin_elementwise_fma(v, w[j + jj], acc);
      }
    }
    part[kh][p][lane] = acc.x;
    part[kh][p][lane + 64] = acc.y;
  }
  __syncthreads();

#pragma unroll
  for (int i = 0; i < 8; ++i) {
    const int e = tid + 256 * i;  // 2048 outputs
    const int p = e >> 7, c = e & 127;
    out[(size_t)(n0 + p) * 128 + c] = part[0][p][c] + part[1][p][c] + bf[c];
  }
}

// ---------------------------------------------------------------------------
// Workspace: nbr@0 (2MB), x1@2MB (8MB). x2 lives in d_out (enc3 in-place).
// ---------------------------------------------------------------------------
extern "C" void kernel_launch(void* const* d_in, const int* in_sizes, int n_in,
                              void* d_out, int out_size, void* d_ws, size_t ws_size,
                              hipStream_t stream) {
  const float* feats = (const float*)d_in[0];
  const float* W1 = (const float*)d_in[1];
  const float* b1 = (const float*)d_in[2];
  const float* W2 = (const float*)d_in[3];
  const float* b2 = (const float*)d_in[4];
  const float* Wf = (const float*)d_in[5];
  const float* bf = (const float*)d_in[6];
  float* out = (float*)d_out;

  char* ws = (char*)d_ws;
  int* nbr = (int*)ws;
  float* x1 = (float*)(ws + (size_t)(2 << 20));
  float* x2 = out;

  knn_kernel<<<512, 512, 0, stream>>>(feats, nbr);
  enc1_kernel<<<512, 256, 0, stream>>>(feats, nbr, W1, b1, x1);
  enc2_kernel<<<2048, 256, 0, stream>>>(x1, nbr, W2, b2, x2);
  enc3_kernel<<<2048, 256, 0, stream>>>(x2, Wf, bf, out);
}